// Round 8
// baseline (446.162 us; speedup 1.0000x reference)
//
#include <hip/hip_runtime.h>
#include <hip/hip_bf16.h>

typedef __attribute__((ext_vector_type(8))) short short8;   // 8 bf16 (A/B frag)
typedef __attribute__((ext_vector_type(4))) short bf16x4;   // 4 bf16 (8B store)
typedef __attribute__((ext_vector_type(4))) float f32x4;    // 4 fp32 (C/D frag)

// b=32, C=128, n=4096, heads=4, dh=32. All I/O fp32; MFMA bf16, fp32 accum.
// SINGLE fused kernel (regular launch, graph-capture-safe), grid 512 = 32 b x 16
// groups, co-resident by __launch_bounds__(256,2) (2 blocks/CU x 256 CU = 512).
// Software global barrier: per-instance counters in ws, zeroed by hipMemsetAsync
// before each launch (so every graph replay resets them). grid.sync()/cooperative
// launch is NOT capture-safe (round-7 failure: barrier never ran -> phases read
// prior-iteration data; nondeterministic 468 / 4.5e-3 errors).
// Phases (bodies verbatim from proven round-6 kernels):
//   W: pack Wf frag-major + gs
//   A: rmsnorm + MFMA qkv + q-softmax + MFMA S/Z partials (68us k1)
//   B: reduce partials + context + fold w_out -> Mtf
//   C: out = Mtf x q + b_out; 4 tiles/block = SAME tiles this block wrote in A
//      (qbf read stays same-XCD-L2-warm; Mtf A-frags loaded once for 4 tiles)
//
// ws (float units):
//   Sp  bf16 frag-major [32][16][4096] @ 0
//   Zp  bf16 [32][16][128]  @ 2097152   (uses 32768 fl; barrier cnt @ 2129920)
//   Mtf bf16 frag-major     @ 2162688
//   Wf  bf16 frag-major     @ 2424832
//   gs  [128]               @ 2449408
//   qbf bf16 frag-major     @ 2449536

__device__ __forceinline__ unsigned short f2bf(float f) {  // RNE, finite inputs
  unsigned u = __float_as_uint(f);
  u += 0x7fff + ((u >> 16) & 1);
  return (unsigned short)(u >> 16);
}
__device__ __forceinline__ float bf2f(unsigned short s) {
  return __uint_as_float(((unsigned)s) << 16);
}

// graph-capture-safe grid barrier: counter pre-zeroed by hipMemsetAsync.
__device__ __forceinline__ void gbar(unsigned* c, unsigned nb) {
  __threadfence();          // release: flush this block's writes (agent scope)
  __syncthreads();          // all threads of block done writing
  if (threadIdx.x == 0) {
    atomicAdd(c, 1u);       // device-scope by default
    while (__hip_atomic_load(c, __ATOMIC_RELAXED, __HIP_MEMORY_SCOPE_AGENT) < nb)
      __builtin_amdgcn_s_sleep(2);
  }
  __syncthreads();
  __threadfence();          // acquire: invalidate stale cached views
}

__global__ __launch_bounds__(256, 2) void fused(
    const float* __restrict__ x, const float* __restrict__ gvec,
    const float* __restrict__ wqkv, const float* __restrict__ memkv,
    const float* __restrict__ wout, const float* __restrict__ bout,
    float* __restrict__ out, float* __restrict__ ws) {
  __shared__ __align__(16) unsigned char smem[50176];   // phase-aliased LDS

  const int bid = blockIdx.x;
  const int b = bid >> 4, grp = bid & 15;
  const int tid = threadIdx.x;
  const int p = tid & 63, w = tid >> 6;
  const int chunk = __builtin_amdgcn_readfirstlane(w);   // wave id == head id
  const int l = p, quad = l >> 4, l16 = l & 15;

  unsigned short* Sp  = (unsigned short*)ws;
  unsigned short* Zp  = (unsigned short*)(ws + 2097152);
  unsigned*       cnt = (unsigned*)(ws + 2129920);       // 3 barrier counters
  unsigned short* Mtf = (unsigned short*)(ws + 2162688);
  unsigned short* Wf  = (unsigned short*)(ws + 2424832);
  float* gs           = ws + 2449408;
  unsigned short* qbf = (unsigned short*)(ws + 2449536);

  // ---------------- phase W: pack Wf frag-major + gs ----------------
  {
    int gtid = bid * 256 + tid;
    if (gtid < 49152) {
      int o = gtid >> 7, c = gtid & 127;
      int f = (o >> 4) * 4 + (c >> 5);
      int lane = (o & 15) + (((c >> 3) & 3) << 4);
      Wf[f * 512 + lane * 8 + (c & 7)] = f2bf(wqkv[o * 128 + c]);
    }
    if (gtid < 128) gs[gtid] = gvec[gtid] * 11.313708498984761f;  // sqrt(128)
  }
  gbar(cnt + 0, 512);

  // ---------------- phase A: k1 (proven 68us body, verbatim) ----------------
  {
    unsigned short* xnf  = (unsigned short*)smem;            // 16 KB
    unsigned short* kbuf = (unsigned short*)(smem + 16384);  // 16 KB, XOR-swizzled
    unsigned short* vbuf = (unsigned short*)(smem + 32768);  // 16 KB, XOR-swizzled
    float* ssred         = (float*)(smem + 49152);           // 1 KB

    short8 ones;               // bf16 1.0 in every slot (B operand for Z row-sums)
#pragma unroll
    for (int j = 0; j < 8; j++) ones[j] = (short)0x3F80;

    f32x4 accS[2][2] = {};     // S partial: [d-block][e-block], head = chunk
    f32x4 accZ[2] = {};        // Z partial: [d-block] (cols replicated)

    const float* xbase = x + (size_t)b * 524288;
    float xr[32];
    {  // prologue: load tile grp*4's column (c = chunk*32+i) for pixel p
      const float* xb = xbase + grp * 256 + p;
#pragma unroll
      for (int i = 0; i < 32; i++) xr[i] = xb[(size_t)(chunk * 32 + i) * 4096];
    }

#pragma unroll 1
    for (int t = 0; t < 4; t++) {
      const int tile = grp * 4 + t;
      float ss = 0.f;
#pragma unroll
      for (int i = 0; i < 32; i++) ss += xr[i] * xr[i];
      ssred[w * 64 + p] = ss;
      __syncthreads();  // (A) also fences prev iter's kbuf/vbuf readers
      float tot = ssred[p] + ssred[64 + p] + ssred[128 + p] + ssred[192 + p];
      float inv = 1.0f / fmaxf(sqrtf(tot), 1e-12f);
#pragma unroll
      for (int q8 = 0; q8 < 4; q8++) {
        short8 v8;
#pragma unroll
        for (int j = 0; j < 8; j++) {
          int i = q8 * 8 + j;
          v8[j] = (short)f2bf(xr[i] * gs[chunk * 32 + i] * inv);
        }
        *(short8*)&xnf[(chunk * 4 + (p >> 4)) * 512 + ((p & 15) + q8 * 16) * 8] = v8;
      }
      __syncthreads();  // (B) xnf ready

      if (t < 3) {
        const float* xb = xbase + (tile + 1) * 64 + p;
#pragma unroll
        for (int i = 0; i < 32; i++) xr[i] = xb[(size_t)(chunk * 32 + i) * 4096];
      }

      const short8* Wfv = (const short8*)Wf;
#pragma unroll
      for (int s = 0; s < 3; s++) {
        f32x4 acc[2][4] = {};
#pragma unroll
        for (int k0 = 0; k0 < 4; k0++) {
          short8 bfr[4];
#pragma unroll
          for (int n0 = 0; n0 < 4; n0++)
            bfr[n0] = *(const short8*)&xnf[(k0 * 4 + n0) * 512 + l * 8];
#pragma unroll
          for (int off = 0; off < 2; off++) {
            short8 afr = Wfv[((s * 8 + chunk * 2 + off) * 4 + k0) * 64 + l];
#pragma unroll
            for (int n0 = 0; n0 < 4; n0++)
              acc[off][n0] = __builtin_amdgcn_mfma_f32_16x16x32_bf16(afr, bfr[n0], acc[off][n0], 0, 0, 0);
          }
        }
        if (s == 0) {  // q: per-pixel softmax over d, packed 8B global stores
#pragma unroll
          for (int n0 = 0; n0 < 4; n0++) {
            float m = -1e30f;
#pragma unroll
            for (int off = 0; off < 2; off++)
#pragma unroll
              for (int r = 0; r < 4; r++) m = fmaxf(m, acc[off][n0][r]);
            m = fmaxf(m, __shfl_xor(m, 16, 64));
            m = fmaxf(m, __shfl_xor(m, 32, 64));
            float e[2][4]; float sum = 0.f;
#pragma unroll
            for (int off = 0; off < 2; off++)
#pragma unroll
              for (int r = 0; r < 4; r++) {
                e[off][r] = __expf(acc[off][n0][r] - m);
                sum += e[off][r];
              }
            sum += __shfl_xor(sum, 16, 64);
            sum += __shfl_xor(sum, 32, 64);
            float rs = 0.17677669529663687f / sum;  // dh^-0.5 / sum
            int qbase = ((b * 64 + tile) * 16 + chunk * 4 + n0) * 512;
#pragma unroll
            for (int off = 0; off < 2; off++) {
              int lane2 = l16 + ((off * 2 + (quad >> 1)) << 4);
              bf16x4 qv;
#pragma unroll
              for (int r = 0; r < 4; r++) qv[r] = (short)f2bf(e[off][r] * rs);
              *(bf16x4*)&qbf[qbase + lane2 * 8 + (quad & 1) * 4] = qv;
            }
          }
        } else if (s == 1) {  // k -> exp -> swizzled LDS (wave-private rows)
#pragma unroll
          for (int off = 0; off < 2; off++)
#pragma unroll
            for (int n0 = 0; n0 < 4; n0++)
#pragma unroll
              for (int r = 0; r < 4; r++) {
                int row = off * 16 + quad * 4 + r;
                int px = n0 * 16 + l16;
                kbuf[(chunk * 32 + row) * 64 + (px ^ ((row & 7) << 3))] = f2bf(__expf(acc[off][n0][r]));
              }
        } else {  // v -> swizzled LDS (wave-private rows)
#pragma unroll
          for (int off = 0; off < 2; off++)
#pragma unroll
            for (int n0 = 0; n0 < 4; n0++)
#pragma unroll
              for (int r = 0; r < 4; r++) {
                int row = off * 16 + quad * 4 + r;
                int px = n0 * 16 + l16;
                vbuf[(chunk * 32 + row) * 64 + (px ^ ((row & 7) << 3))] = f2bf(acc[off][n0][r]);
              }
        }
      }

      // phase 4: S/Z via MFMA (own head's rows only; same-wave RAW, no barrier)
      const unsigned short* kb = kbuf + chunk * 2048;
      const unsigned short* vb = vbuf + chunk * 2048;
#pragma unroll
      for (int kk = 0; kk < 2; kk++) {
        int cofs = (kk * 32 + quad * 8) ^ ((l16 & 7) << 3);
        short8 ak[2], av[2];
#pragma unroll
        for (int mm = 0; mm < 2; mm++) {
          ak[mm] = *(const short8*)&kb[(mm * 16 + l16) * 64 + cofs];
          av[mm] = *(const short8*)&vb[(mm * 16 + l16) * 64 + cofs];
        }
#pragma unroll
        for (int mm = 0; mm < 2; mm++) {
#pragma unroll
          for (int nn = 0; nn < 2; nn++)
            accS[mm][nn] = __builtin_amdgcn_mfma_f32_16x16x32_bf16(ak[mm], av[nn], accS[mm][nn], 0, 0, 0);
          accZ[mm] = __builtin_amdgcn_mfma_f32_16x16x32_bf16(ak[mm], ones, accZ[mm], 0, 0, 0);
        }
      }
    }

    // write bf16 partials frag-major (coalesced 8B stores, no atomics)
    unsigned short* Spb = Sp + (size_t)(b * 16 + grp) * 4096 + chunk * 1024;
#pragma unroll
    for (int mm = 0; mm < 2; mm++)
#pragma unroll
      for (int nn = 0; nn < 2; nn++) {
        bf16x4 sv;
#pragma unroll
        for (int r = 0; r < 4; r++) sv[r] = (short)f2bf(accS[mm][nn][r]);
        *(bf16x4*)&Spb[(mm * 2 + nn) * 256 + l * 4] = sv;
      }
    if (l16 == 0) {
#pragma unroll
      for (int mm = 0; mm < 2; mm++) {
        bf16x4 zv;
#pragma unroll
        for (int r = 0; r < 4; r++) zv[r] = (short)f2bf(accZ[mm][r]);
        *(bf16x4*)&Zp[(b * 16 + grp) * 128 + chunk * 32 + mm * 16 + quad * 4] = zv;
      }
    }
  }
  gbar(cnt + 1, 512);

  // ---------------- phase B: k2 (round-6 body, verbatim; sl = grp) ----------------
  {
    float* wl     = (float*)smem;             // 128*33 staged wout, padded
    float* Cs     = (float*)(smem + 16896);   // 8*32 context rows
    float* zsh    = (float*)(smem + 17920);
    float* zinv_s = (float*)(smem + 17952);
    const int sl = grp;
    const int hd0 = sl * 8, h = hd0 >> 5;
    for (int i = tid; i < 4096; i += 256) {
      int o = i >> 5, e = i & 31;
      wl[o * 33 + e] = wout[o * 128 + h * 32 + e];
    }
    {
      int hdi = tid >> 5, g = tid & 31;
      float zp = (g < 16) ? bf2f(Zp[(b * 16 + g) * 128 + hd0 + hdi]) : 0.f;
#pragma unroll
      for (int s2 = 1; s2 < 32; s2 <<= 1) zp += __shfl_xor(zp, s2, 32);
      if (g == 0) zsh[hdi] = zp;
    }
    __syncthreads();
    if (tid < 8) {
      int hd = hd0 + tid;
      float zm = 0.f;
#pragma unroll
      for (int j = 0; j < 4; j++) zm += __expf(memkv[hd * 4 + j]);
      zinv_s[tid] = 1.0f / (zsh[tid] + zm);
    }
    __syncthreads();
    {
      int hdi = tid >> 5, e = tid & 31;
      int hd = hd0 + hdi, d = hd & 31;
      int fofs = h * 1024 + ((d >> 4) * 2 + (e >> 4)) * 256 + ((e & 15) + ((d >> 2) & 3) * 16) * 4 + (d & 3);
      const unsigned short* Spb = Sp + (size_t)b * 65536 + fofs;
      float s = 0.f;
#pragma unroll
      for (int g = 0; g < 16; g++) s += bf2f(Spb[g * 4096]);
      float sm = 0.f;
#pragma unroll
      for (int j = 0; j < 4; j++)
        sm += __expf(memkv[hd * 4 + j]) * memkv[512 + (h * 32 + e) * 4 + j];
      Cs[hdi * 32 + e] = (s + sm) * zinv_s[hdi];
    }
    __syncthreads();
    for (int i = tid; i < 1024; i += 256) {
      int o = i & 127, hdi = i >> 7;
      float a = 0.f;
#pragma unroll
      for (int e = 0; e < 32; e++) a += wl[o * 33 + e] * Cs[hdi * 32 + e];
      int hd = hd0 + hdi;
      int f = (o >> 4) * 4 + h;
      int lane = (o & 15) + (((hd >> 3) & 3) << 4);
      Mtf[(size_t)b * 16384 + f * 512 + lane * 8 + (hd & 7)] = f2bf(a);
    }
  }
  gbar(cnt + 2, 512);

  // ---------------- phase C: out = Mtf x q + b_out (4 tiles, same as phase A's) ----------------
  {
    const short8* Mv = (const short8*)Mtf;
    short8 afr[2][4];   // loaded ONCE, reused across 4 tiles
#pragma unroll
    for (int mm = 0; mm < 2; mm++)
#pragma unroll
      for (int k0 = 0; k0 < 4; k0++)
        afr[mm][k0] = Mv[((size_t)b * 32 + (chunk * 2 + mm) * 4 + k0) * 64 + l];
    float* obb = out + (size_t)b * 524288;
#pragma unroll 1
    for (int t = 0; t < 4; t++) {
      const int tile = grp * 4 + t;
      const short8* qv = (const short8*)qbf + (size_t)(b * 64 + tile) * 1024;
      f32x4 acc[2][4] = {};
#pragma unroll
      for (int hh = 0; hh < 2; hh++) {   // frag halves: k0 = 2hh, 2hh+1
        short8 bfr[8];
#pragma unroll
        for (int j = 0; j < 8; j++) bfr[j] = qv[(hh * 8 + j) * 64 + l];
#pragma unroll
        for (int kk = 0; kk < 2; kk++) {
          int k0 = hh * 2 + kk;
#pragma unroll
          for (int mm = 0; mm < 2; mm++)
#pragma unroll
            for (int n0 = 0; n0 < 4; n0++)
              acc[mm][n0] = __builtin_amdgcn_mfma_f32_16x16x32_bf16(afr[mm][k0], bfr[kk * 4 + n0], acc[mm][n0], 0, 0, 0);
        }
      }
      float* ob = obb + tile * 64;
#pragma unroll
      for (int mm = 0; mm < 2; mm++)
#pragma unroll
        for (int r = 0; r < 4; r++) {
          int o = chunk * 32 + mm * 16 + quad * 4 + r;
          float bv = bout[o];
#pragma unroll
          for (int n0 = 0; n0 < 4; n0++)
            ob[(size_t)o * 4096 + n0 * 16 + l16] = acc[mm][n0][r] + bv;
        }
    }
  }
}

extern "C" void kernel_launch(void* const* d_in, const int* in_sizes, int n_in,
                              void* d_out, int out_size, void* d_ws, size_t ws_size,
                              hipStream_t stream) {
  const float* x     = (const float*)d_in[0];
  const float* g     = (const float*)d_in[1];
  const float* wqkv  = (const float*)d_in[2];
  const float* memkv = (const float*)d_in[3];
  const float* wout  = (const float*)d_in[4];
  const float* bout  = (const float*)d_in[5];
  float* out = (float*)d_out;
  float* ws = (float*)d_ws;

  // zero the 3 barrier counters (byte offset 2129920*4 = 8519680; first free
  // byte after Zp's used 131072 B). Captured into the graph -> resets每 replay.
  hipMemsetAsync((char*)d_ws + 8519680, 0, 16, stream);
  fused<<<512, 256, 0, stream>>>(x, g, wqkv, memkv, wout, bout, out, ws);
}

// Round 9
// 212.079 us; speedup vs baseline: 2.1038x; 2.1038x over previous
//
#include <hip/hip_runtime.h>
#include <hip/hip_bf16.h>

typedef __attribute__((ext_vector_type(8))) short short8;   // 8 bf16 (A/B frag)
typedef __attribute__((ext_vector_type(4))) short bf16x4;   // 4 bf16 (8B store)
typedef __attribute__((ext_vector_type(4))) float f32x4;    // 4 fp32 (C/D frag)

// b=32, C=128, n=4096, heads=4, dh=32. All I/O fp32; MFMA bf16, fp32 accum.
// k0 (tiny launch) + ONE fused kernel (A/B/C), grid 512 = 32 b x 16 groups,
// co-resident by __launch_bounds__(256,2) (2 blocks/CU x 256 CU = 512; LDS 50K -> 3/CU ok).
// Graph-capture-safe software grid barrier, cost-optimized vs round 8:
//   - ONE __threadfence per block per side (tid==0), not per thread: syncthreads
//     drains all waves' vmcnt into L2; wbl2/inv are L2-wide cache ops so a single
//     executor suffices. Round 8's per-thread fences = 786k wbl2/inv executions
//     (~250us); this is 1024.
//   - 8-leaf tree counters (128B apart) kill the 512-way single-line RMW serialization.
//   - counters pre-zeroed by hipMemsetAsync (captured -> resets every graph replay).
// Phases (bodies verbatim from proven round-6 kernels):
//   A: rmsnorm + MFMA qkv + q-softmax + MFMA S/Z partials (68us k1)
//   B: reduce partials + context + fold w_out -> Mtf
//   C: out = Mtf x q + b_out; 4 tiles/block = SAME tiles this block wrote in A
//
// ws (float units):
//   Sp  bf16 frag-major [32][16][4096] @ 0
//   Zp  bf16 [32][16][128]  @ 2097152   (uses 32768 fl; barrier cnts @ 2129920, 4KB)
//   Mtf bf16 frag-major     @ 2162688
//   Wf  bf16 frag-major     @ 2424832
//   gs  [128]               @ 2449408
//   qbf bf16 frag-major     @ 2449536

__device__ __forceinline__ unsigned short f2bf(float f) {  // RNE, finite inputs
  unsigned u = __float_as_uint(f);
  u += 0x7fff + ((u >> 16) & 1);
  return (unsigned short)(u >> 16);
}
__device__ __forceinline__ float bf2f(unsigned short s) {
  return __uint_as_float(((unsigned)s) << 16);
}

// graph-capture-safe grid barrier; counters pre-zeroed by hipMemsetAsync.
// base: 512 u32 region. leaves at base + (bid&7)*32 (128B apart), root at base+256.
__device__ __forceinline__ void gbar(unsigned* base, int bid) {
  __syncthreads();   // all waves' stores issued & vmcnt drained (into local L2)
  if (threadIdx.x == 0) {
    __threadfence(); // release: wbl2 (L2-wide) + waitcnt -> writes at coherence point
    unsigned* leaf = base + (bid & 7) * 32;
    unsigned* root = base + 256;
    if (atomicAdd(leaf, 1u) == 63u) atomicAdd(root, 1u);  // last of 64 promotes
    while (__hip_atomic_load(root, __ATOMIC_RELAXED, __HIP_MEMORY_SCOPE_AGENT) != 8u)
      __builtin_amdgcn_s_sleep(4);
    __threadfence(); // acquire: inv stale L1/L2 before any post-barrier reads
  }
  __syncthreads();   // hold other waves until inv complete
}

// ---------------- K0: pack Wf frag-major, gs (separate launch) ----------------
__global__ void k0_init(const float* __restrict__ wqkv, const float* __restrict__ g,
                        float* __restrict__ ws) {
  int tid = blockIdx.x * blockDim.x + threadIdx.x;
  int stride = gridDim.x * blockDim.x;
  unsigned short* Wf = (unsigned short*)(ws + 2424832);
  for (int i = tid; i < 49152; i += stride) {
    int o = i >> 7, c = i & 127;
    int f = (o >> 4) * 4 + (c >> 5);
    int lane = (o & 15) + (((c >> 3) & 3) << 4);
    Wf[f * 512 + lane * 8 + (c & 7)] = f2bf(wqkv[o * 128 + c]);
  }
  float* gs = ws + 2449408;
  if (tid < 128) gs[tid] = g[tid] * 11.313708498984761f;  // sqrt(128)
}

__global__ __launch_bounds__(256, 2) void fused(
    const float* __restrict__ x, const float* __restrict__ memkv,
    const float* __restrict__ wout, const float* __restrict__ bout,
    float* __restrict__ out, float* __restrict__ ws) {
  __shared__ __align__(16) unsigned char smem[50176];   // phase-aliased LDS

  const int bid = blockIdx.x;
  const int b = bid >> 4, grp = bid & 15;
  const int tid = threadIdx.x;
  const int p = tid & 63, w = tid >> 6;
  const int chunk = __builtin_amdgcn_readfirstlane(w);   // wave id == head id
  const int l = p, quad = l >> 4, l16 = l & 15;

  unsigned short* Sp  = (unsigned short*)ws;
  unsigned short* Zp  = (unsigned short*)(ws + 2097152);
  unsigned*       cnt = (unsigned*)(ws + 2129920);       // 2 barriers x 512 u32
  unsigned short* Mtf = (unsigned short*)(ws + 2162688);
  unsigned short* Wf  = (unsigned short*)(ws + 2424832);
  float* gs           = ws + 2449408;
  unsigned short* qbf = (unsigned short*)(ws + 2449536);

  // ---------------- phase A: k1 (proven 68us body, verbatim) ----------------
  {
    unsigned short* xnf  = (unsigned short*)smem;            // 16 KB
    unsigned short* kbuf = (unsigned short*)(smem + 16384);  // 16 KB, XOR-swizzled
    unsigned short* vbuf = (unsigned short*)(smem + 32768);  // 16 KB, XOR-swizzled
    float* ssred         = (float*)(smem + 49152);           // 1 KB

    short8 ones;               // bf16 1.0 in every slot (B operand for Z row-sums)
#pragma unroll
    for (int j = 0; j < 8; j++) ones[j] = (short)0x3F80;

    f32x4 accS[2][2] = {};     // S partial: [d-block][e-block], head = chunk
    f32x4 accZ[2] = {};        // Z partial: [d-block] (cols replicated)

    const float* xbase = x + (size_t)b * 524288;
    float xr[32];
    {  // prologue: load tile grp*4's column (c = chunk*32+i) for pixel p
      const float* xb = xbase + grp * 256 + p;
#pragma unroll
      for (int i = 0; i < 32; i++) xr[i] = xb[(size_t)(chunk * 32 + i) * 4096];
    }

#pragma unroll 1
    for (int t = 0; t < 4; t++) {
      const int tile = grp * 4 + t;
      float ss = 0.f;
#pragma unroll
      for (int i = 0; i < 32; i++) ss += xr[i] * xr[i];
      ssred[w * 64 + p] = ss;
      __syncthreads();  // (A) also fences prev iter's kbuf/vbuf readers
      float tot = ssred[p] + ssred[64 + p] + ssred[128 + p] + ssred[192 + p];
      float inv = 1.0f / fmaxf(sqrtf(tot), 1e-12f);
#pragma unroll
      for (int q8 = 0; q8 < 4; q8++) {
        short8 v8;
#pragma unroll
        for (int j = 0; j < 8; j++) {
          int i = q8 * 8 + j;
          v8[j] = (short)f2bf(xr[i] * gs[chunk * 32 + i] * inv);
        }
        *(short8*)&xnf[(chunk * 4 + (p >> 4)) * 512 + ((p & 15) + q8 * 16) * 8] = v8;
      }
      __syncthreads();  // (B) xnf ready

      if (t < 3) {
        const float* xb = xbase + (tile + 1) * 64 + p;
#pragma unroll
        for (int i = 0; i < 32; i++) xr[i] = xb[(size_t)(chunk * 32 + i) * 4096];
      }

      const short8* Wfv = (const short8*)Wf;
#pragma unroll
      for (int s = 0; s < 3; s++) {
        f32x4 acc[2][4] = {};
#pragma unroll
        for (int k0 = 0; k0 < 4; k0++) {
          short8 bfr[4];
#pragma unroll
          for (int n0 = 0; n0 < 4; n0++)
            bfr[n0] = *(const short8*)&xnf[(k0 * 4 + n0) * 512 + l * 8];
#pragma unroll
          for (int off = 0; off < 2; off++) {
            short8 afr = Wfv[((s * 8 + chunk * 2 + off) * 4 + k0) * 64 + l];
#pragma unroll
            for (int n0 = 0; n0 < 4; n0++)
              acc[off][n0] = __builtin_amdgcn_mfma_f32_16x16x32_bf16(afr, bfr[n0], acc[off][n0], 0, 0, 0);
          }
        }
        if (s == 0) {  // q: per-pixel softmax over d, packed 8B global stores
#pragma unroll
          for (int n0 = 0; n0 < 4; n0++) {
            float m = -1e30f;
#pragma unroll
            for (int off = 0; off < 2; off++)
#pragma unroll
              for (int r = 0; r < 4; r++) m = fmaxf(m, acc[off][n0][r]);
            m = fmaxf(m, __shfl_xor(m, 16, 64));
            m = fmaxf(m, __shfl_xor(m, 32, 64));
            float e[2][4]; float sum = 0.f;
#pragma unroll
            for (int off = 0; off < 2; off++)
#pragma unroll
              for (int r = 0; r < 4; r++) {
                e[off][r] = __expf(acc[off][n0][r] - m);
                sum += e[off][r];
              }
            sum += __shfl_xor(sum, 16, 64);
            sum += __shfl_xor(sum, 32, 64);
            float rs = 0.17677669529663687f / sum;  // dh^-0.5 / sum
            int qbase = ((b * 64 + tile) * 16 + chunk * 4 + n0) * 512;
#pragma unroll
            for (int off = 0; off < 2; off++) {
              int lane2 = l16 + ((off * 2 + (quad >> 1)) << 4);
              bf16x4 qv;
#pragma unroll
              for (int r = 0; r < 4; r++) qv[r] = (short)f2bf(e[off][r] * rs);
              *(bf16x4*)&qbf[qbase + lane2 * 8 + (quad & 1) * 4] = qv;
            }
          }
        } else if (s == 1) {  // k -> exp -> swizzled LDS (wave-private rows)
#pragma unroll
          for (int off = 0; off < 2; off++)
#pragma unroll
            for (int n0 = 0; n0 < 4; n0++)
#pragma unroll
              for (int r = 0; r < 4; r++) {
                int row = off * 16 + quad * 4 + r;
                int px = n0 * 16 + l16;
                kbuf[(chunk * 32 + row) * 64 + (px ^ ((row & 7) << 3))] = f2bf(__expf(acc[off][n0][r]));
              }
        } else {  // v -> swizzled LDS (wave-private rows)
#pragma unroll
          for (int off = 0; off < 2; off++)
#pragma unroll
            for (int n0 = 0; n0 < 4; n0++)
#pragma unroll
              for (int r = 0; r < 4; r++) {
                int row = off * 16 + quad * 4 + r;
                int px = n0 * 16 + l16;
                vbuf[(chunk * 32 + row) * 64 + (px ^ ((row & 7) << 3))] = f2bf(acc[off][n0][r]);
              }
        }
      }

      // phase 4: S/Z via MFMA (own head's rows only; same-wave RAW, no barrier)
      const unsigned short* kb = kbuf + chunk * 2048;
      const unsigned short* vb = vbuf + chunk * 2048;
#pragma unroll
      for (int kk = 0; kk < 2; kk++) {
        int cofs = (kk * 32 + quad * 8) ^ ((l16 & 7) << 3);
        short8 ak[2], av[2];
#pragma unroll
        for (int mm = 0; mm < 2; mm++) {
          ak[mm] = *(const short8*)&kb[(mm * 16 + l16) * 64 + cofs];
          av[mm] = *(const short8*)&vb[(mm * 16 + l16) * 64 + cofs];
        }
#pragma unroll
        for (int mm = 0; mm < 2; mm++) {
#pragma unroll
          for (int nn = 0; nn < 2; nn++)
            accS[mm][nn] = __builtin_amdgcn_mfma_f32_16x16x32_bf16(ak[mm], av[nn], accS[mm][nn], 0, 0, 0);
          accZ[mm] = __builtin_amdgcn_mfma_f32_16x16x32_bf16(ak[mm], ones, accZ[mm], 0, 0, 0);
        }
      }
    }

    // write bf16 partials frag-major (coalesced 8B stores, no atomics)
    unsigned short* Spb = Sp + (size_t)(b * 16 + grp) * 4096 + chunk * 1024;
#pragma unroll
    for (int mm = 0; mm < 2; mm++)
#pragma unroll
      for (int nn = 0; nn < 2; nn++) {
        bf16x4 sv;
#pragma unroll
        for (int r = 0; r < 4; r++) sv[r] = (short)f2bf(accS[mm][nn][r]);
        *(bf16x4*)&Spb[(mm * 2 + nn) * 256 + l * 4] = sv;
      }
    if (l16 == 0) {
#pragma unroll
      for (int mm = 0; mm < 2; mm++) {
        bf16x4 zv;
#pragma unroll
        for (int r = 0; r < 4; r++) zv[r] = (short)f2bf(accZ[mm][r]);
        *(bf16x4*)&Zp[(b * 16 + grp) * 128 + chunk * 32 + mm * 16 + quad * 4] = zv;
      }
    }
  }
  gbar(cnt, bid);

  // ---------------- phase B: k2 (round-6 body, verbatim; sl = grp) ----------------
  {
    float* wl     = (float*)smem;             // 128*33 staged wout, padded
    float* Cs     = (float*)(smem + 16896);   // 8*32 context rows
    float* zsh    = (float*)(smem + 17920);
    float* zinv_s = (float*)(smem + 17952);
    const int sl = grp;
    const int hd0 = sl * 8, h = hd0 >> 5;
    for (int i = tid; i < 4096; i += 256) {
      int o = i >> 5, e = i & 31;
      wl[o * 33 + e] = wout[o * 128 + h * 32 + e];
    }
    {
      int hdi = tid >> 5, g = tid & 31;
      float zp = (g < 16) ? bf2f(Zp[(b * 16 + g) * 128 + hd0 + hdi]) : 0.f;
#pragma unroll
      for (int s2 = 1; s2 < 32; s2 <<= 1) zp += __shfl_xor(zp, s2, 32);
      if (g == 0) zsh[hdi] = zp;
    }
    __syncthreads();
    if (tid < 8) {
      int hd = hd0 + tid;
      float zm = 0.f;
#pragma unroll
      for (int j = 0; j < 4; j++) zm += __expf(memkv[hd * 4 + j]);
      zinv_s[tid] = 1.0f / (zsh[tid] + zm);
    }
    __syncthreads();
    {
      int hdi = tid >> 5, e = tid & 31;
      int hd = hd0 + hdi, d = hd & 31;
      int fofs = h * 1024 + ((d >> 4) * 2 + (e >> 4)) * 256 + ((e & 15) + ((d >> 2) & 3) * 16) * 4 + (d & 3);
      const unsigned short* Spb = Sp + (size_t)b * 65536 + fofs;
      float s = 0.f;
#pragma unroll
      for (int g = 0; g < 16; g++) s += bf2f(Spb[g * 4096]);
      float sm = 0.f;
#pragma unroll
      for (int j = 0; j < 4; j++)
        sm += __expf(memkv[hd * 4 + j]) * memkv[512 + (h * 32 + e) * 4 + j];
      Cs[hdi * 32 + e] = (s + sm) * zinv_s[hdi];
    }
    __syncthreads();
    for (int i = tid; i < 1024; i += 256) {
      int o = i & 127, hdi = i >> 7;
      float a = 0.f;
#pragma unroll
      for (int e = 0; e < 32; e++) a += wl[o * 33 + e] * Cs[hdi * 32 + e];
      int hd = hd0 + hdi;
      int f = (o >> 4) * 4 + h;
      int lane = (o & 15) + (((hd >> 3) & 3) << 4);
      Mtf[(size_t)b * 16384 + f * 512 + lane * 8 + (hd & 7)] = f2bf(a);
    }
  }
  gbar(cnt + 512, bid);

  // ---------------- phase C: out = Mtf x q + b_out (4 tiles, same as phase A's) ----------------
  {
    const short8* Mv = (const short8*)Mtf;
    short8 afr[2][4];   // loaded ONCE, reused across 4 tiles
#pragma unroll
    for (int mm = 0; mm < 2; mm++)
#pragma unroll
      for (int k0 = 0; k0 < 4; k0++)
        afr[mm][k0] = Mv[((size_t)b * 32 + (chunk * 2 + mm) * 4 + k0) * 64 + l];
    float* obb = out + (size_t)b * 524288;
#pragma unroll 1
    for (int t = 0; t < 4; t++) {
      const int tile = grp * 4 + t;
      const short8* qv = (const short8*)qbf + (size_t)(b * 64 + tile) * 1024;
      f32x4 acc[2][4] = {};
#pragma unroll
      for (int hh = 0; hh < 2; hh++) {   // frag halves: k0 = 2hh, 2hh+1
        short8 bfr[8];
#pragma unroll
        for (int j = 0; j < 8; j++) bfr[j] = qv[(hh * 8 + j) * 64 + l];
#pragma unroll
        for (int kk = 0; kk < 2; kk++) {
          int k0 = hh * 2 + kk;
#pragma unroll
          for (int mm = 0; mm < 2; mm++)
#pragma unroll
            for (int n0 = 0; n0 < 4; n0++)
              acc[mm][n0] = __builtin_amdgcn_mfma_f32_16x16x32_bf16(afr[mm][k0], bfr[kk * 4 + n0], acc[mm][n0], 0, 0, 0);
        }
      }
      float* ob = obb + tile * 64;
#pragma unroll
      for (int mm = 0; mm < 2; mm++)
#pragma unroll
        for (int r = 0; r < 4; r++) {
          int o = chunk * 32 + mm * 16 + quad * 4 + r;
          float bv = bout[o];
#pragma unroll
          for (int n0 = 0; n0 < 4; n0++)
            ob[(size_t)o * 4096 + n0 * 16 + l16] = acc[mm][n0][r] + bv;
        }
    }
  }
}

extern "C" void kernel_launch(void* const* d_in, const int* in_sizes, int n_in,
                              void* d_out, int out_size, void* d_ws, size_t ws_size,
                              hipStream_t stream) {
  const float* x     = (const float*)d_in[0];
  const float* g     = (const float*)d_in[1];
  const float* wqkv  = (const float*)d_in[2];
  const float* memkv = (const float*)d_in[3];
  const float* wout  = (const float*)d_in[4];
  const float* bout  = (const float*)d_in[5];
  float* out = (float*)d_out;
  float* ws = (float*)d_ws;

  // zero the barrier counters (bytes 8519680..+4096, tail of the Zp region);
  // captured into the graph -> resets every replay.
  hipMemsetAsync((char*)d_ws + 8519680, 0, 4096, stream);
  k0_init<<<128, 256, 0, stream>>>(wqkv, g, ws);
  fused<<<512, 256, 0, stream>>>(x, memkv, wout, bout, out, ws);
}

// Round 10
// 186.932 us; speedup vs baseline: 2.3868x; 1.1345x over previous
//
#include <hip/hip_runtime.h>
#include <hip/hip_bf16.h>

typedef __attribute__((ext_vector_type(8))) short short8;   // 8 bf16 (A/B frag)
typedef __attribute__((ext_vector_type(4))) short bf16x4;   // 4 bf16 (8B store)
typedef __attribute__((ext_vector_type(4))) float f32x4;    // 4 fp32 (C/D frag)

// b=32, C=128, n=4096, heads=4, dh=32. All I/O fp32; MFMA bf16, fp32 accum.
// FOUR launches (round-6 config, best measured 187.5us; fusion rejected: r9
// ledger shows harness-fixed ~82us overhead and fused B+C+barriers (55.6us)
// slower than separate k2+k3 (~33us)).
// K1 change this round: the 24 loop-invariant Wf A-frags per wave are hoisted
// into registers BEFORE the tile loop (96 VGPRs; cap 256 at launch_bounds(256,2)).
// The __syncthreads inside the t-loop is a memory barrier, so the compiler
// re-loaded them from global every tile (96 L2-latency loads/wave on the
// critical path). Falsifier: VGPR ~210-235 & WRITE stable => no spill.
//
// ws (float units):
//   Sp  bf16 frag-major [32][16][4096] @ 0
//   Zp  bf16 [32][16][128]  @ 2097152
//   Mtf bf16 frag-major     @ 2162688
//   Wf  bf16 frag-major     @ 2424832
//   gs  [128]               @ 2449408
//   qbf bf16 frag-major     @ 2449536

__device__ __forceinline__ unsigned short f2bf(float f) {  // RNE, finite inputs
  unsigned u = __float_as_uint(f);
  u += 0x7fff + ((u >> 16) & 1);
  return (unsigned short)(u >> 16);
}
__device__ __forceinline__ float bf2f(unsigned short s) {
  return __uint_as_float(((unsigned)s) << 16);
}

// ---------------- K0: pack Wf frag-major, gs ----------------
__global__ void k0_init(const float* __restrict__ wqkv, const float* __restrict__ g,
                        float* __restrict__ ws) {
  int tid = blockIdx.x * blockDim.x + threadIdx.x;
  int stride = gridDim.x * blockDim.x;
  unsigned short* Wf = (unsigned short*)(ws + 2424832);
  for (int i = tid; i < 49152; i += stride) {
    int o = i >> 7, c = i & 127;
    int f = (o >> 4) * 4 + (c >> 5);
    int lane = (o & 15) + (((c >> 3) & 3) << 4);
    Wf[f * 512 + lane * 8 + (c & 7)] = f2bf(wqkv[o * 128 + c]);
  }
  float* gs = ws + 2449408;
  if (tid < 128) gs[tid] = g[tid] * 11.313708498984761f;  // sqrt(128)
}

// ---------------- K1: rmsnorm + MFMA qkv + q-softmax + MFMA S/Z partials ----------------
// grid 512 = 32 b * 16 groups; each block does 4 tiles of 64 px.
__global__ __launch_bounds__(256, 2) void k1_qkv(
    const float* __restrict__ x, const unsigned short* __restrict__ Wf,
    const float* __restrict__ gs, unsigned short* __restrict__ Sp,
    unsigned short* __restrict__ Zp, unsigned short* __restrict__ qbf) {
  __shared__ __align__(16) unsigned short xnf[16 * 512];   // 16 KB: B-frags of xn
  __shared__ __align__(16) unsigned short kbuf[128 * 64];  // 16 KB: exp(k), XOR-swizzled
  __shared__ __align__(16) unsigned short vbuf[128 * 64];  // 16 KB: v, XOR-swizzled
  __shared__ float ssred[256];                             // 1 KB
  const int b = blockIdx.x >> 4, grp = blockIdx.x & 15;
  const int tid = threadIdx.x;
  const int p = tid & 63, w = tid >> 6;
  const int chunk = __builtin_amdgcn_readfirstlane(w);   // wave id == head id
  const int l = p, quad = l >> 4, l16 = l & 15;

  short8 ones;                 // bf16 1.0 in every slot (B operand for Z row-sums)
#pragma unroll
  for (int j = 0; j < 8; j++) ones[j] = (short)0x3F80;

  f32x4 accS[2][2] = {};       // S partial: [d-block][e-block], head = chunk
  f32x4 accZ[2] = {};          // Z partial: [d-block] (cols replicated)

  // hoist the 24 loop-invariant Wf A-frags into registers (96 VGPRs).
  const short8* Wfv = (const short8*)Wf;
  short8 wfr[3][2][4];
#pragma unroll
  for (int s = 0; s < 3; s++)
#pragma unroll
    for (int off = 0; off < 2; off++)
#pragma unroll
      for (int k0 = 0; k0 < 4; k0++)
        wfr[s][off][k0] = Wfv[((s * 8 + chunk * 2 + off) * 4 + k0) * 64 + l];

  const float* xbase = x + (size_t)b * 524288;
  float xr[32];
  {  // prologue: load tile grp*4's column (c = chunk*32+i) for pixel p
    const float* xb = xbase + grp * 256 + p;
#pragma unroll
    for (int i = 0; i < 32; i++) xr[i] = xb[(size_t)(chunk * 32 + i) * 4096];
  }

#pragma unroll 1
  for (int t = 0; t < 4; t++) {
    const int tile = grp * 4 + t;
    // phase 1: rmsnorm on prefetched xr
    float ss = 0.f;
#pragma unroll
    for (int i = 0; i < 32; i++) ss += xr[i] * xr[i];
    ssred[w * 64 + p] = ss;
    __syncthreads();  // (A) also fences prev iter's kbuf/vbuf readers
    float tot = ssred[p] + ssred[64 + p] + ssred[128 + p] + ssred[192 + p];
    float inv = 1.0f / fmaxf(sqrtf(tot), 1e-12f);
#pragma unroll
    for (int q8 = 0; q8 < 4; q8++) {
      short8 v8;
#pragma unroll
      for (int j = 0; j < 8; j++) {
        int i = q8 * 8 + j;
        v8[j] = (short)f2bf(xr[i] * gs[chunk * 32 + i] * inv);
      }
      *(short8*)&xnf[(chunk * 4 + (p >> 4)) * 512 + ((p & 15) + q8 * 16) * 8] = v8;
    }
    __syncthreads();  // (B) xnf ready

    // prefetch next tile's x under the MFMA sections (xr consumed above)
    if (t < 3) {
      const float* xb = xbase + (tile + 1) * 64 + p;
#pragma unroll
      for (int i = 0; i < 32; i++) xr[i] = xb[(size_t)(chunk * 32 + i) * 4096];
    }

    // phase 2+3: each wave does one 32-row section per s: s=0 q, s=1 k, s=2 v
#pragma unroll
    for (int s = 0; s < 3; s++) {
      f32x4 acc[2][4] = {};
#pragma unroll
      for (int k0 = 0; k0 < 4; k0++) {
        short8 bfr[4];
#pragma unroll
        for (int n0 = 0; n0 < 4; n0++)
          bfr[n0] = *(const short8*)&xnf[(k0 * 4 + n0) * 512 + l * 8];
#pragma unroll
        for (int off = 0; off < 2; off++) {
          short8 afr = wfr[s][off][k0];
#pragma unroll
          for (int n0 = 0; n0 < 4; n0++)
            acc[off][n0] = __builtin_amdgcn_mfma_f32_16x16x32_bf16(afr, bfr[n0], acc[off][n0], 0, 0, 0);
        }
      }
      if (s == 0) {  // q: per-pixel softmax over d, packed 8B global stores
#pragma unroll
        for (int n0 = 0; n0 < 4; n0++) {
          float m = -1e30f;
#pragma unroll
          for (int off = 0; off < 2; off++)
#pragma unroll
            for (int r = 0; r < 4; r++) m = fmaxf(m, acc[off][n0][r]);
          m = fmaxf(m, __shfl_xor(m, 16, 64));
          m = fmaxf(m, __shfl_xor(m, 32, 64));
          float e[2][4]; float sum = 0.f;
#pragma unroll
          for (int off = 0; off < 2; off++)
#pragma unroll
            for (int r = 0; r < 4; r++) {
              e[off][r] = __expf(acc[off][n0][r] - m);
              sum += e[off][r];
            }
          sum += __shfl_xor(sum, 16, 64);
          sum += __shfl_xor(sum, 32, 64);
          float rs = 0.17677669529663687f / sum;  // dh^-0.5 / sum
          int qbase = ((b * 64 + tile) * 16 + chunk * 4 + n0) * 512;
#pragma unroll
          for (int off = 0; off < 2; off++) {
            int lane2 = l16 + ((off * 2 + (quad >> 1)) << 4);
            bf16x4 qv;
#pragma unroll
            for (int r = 0; r < 4; r++) qv[r] = (short)f2bf(e[off][r] * rs);
            *(bf16x4*)&qbf[qbase + lane2 * 8 + (quad & 1) * 4] = qv;
          }
        }
      } else if (s == 1) {  // k -> exp -> swizzled LDS (wave-private rows)
#pragma unroll
        for (int off = 0; off < 2; off++)
#pragma unroll
          for (int n0 = 0; n0 < 4; n0++)
#pragma unroll
            for (int r = 0; r < 4; r++) {
              int row = off * 16 + quad * 4 + r;
              int px = n0 * 16 + l16;
              kbuf[(chunk * 32 + row) * 64 + (px ^ ((row & 7) << 3))] = f2bf(__expf(acc[off][n0][r]));
            }
      } else {  // v -> swizzled LDS (wave-private rows)
#pragma unroll
        for (int off = 0; off < 2; off++)
#pragma unroll
          for (int n0 = 0; n0 < 4; n0++)
#pragma unroll
            for (int r = 0; r < 4; r++) {
              int row = off * 16 + quad * 4 + r;
              int px = n0 * 16 + l16;
              vbuf[(chunk * 32 + row) * 64 + (px ^ ((row & 7) << 3))] = f2bf(acc[off][n0][r]);
            }
      }
    }

    // phase 4: S/Z via MFMA over this tile's 64 px (own head's rows only,
    // same-wave RAW through LDS -> no barrier needed; (A) of next iter fences reuse)
    const unsigned short* kb = kbuf + chunk * 2048;
    const unsigned short* vb = vbuf + chunk * 2048;
#pragma unroll
    for (int kk = 0; kk < 2; kk++) {
      int cofs = (kk * 32 + quad * 8) ^ ((l16 & 7) << 3);
      short8 ak[2], av[2];
#pragma unroll
      for (int mm = 0; mm < 2; mm++) {
        ak[mm] = *(const short8*)&kb[(mm * 16 + l16) * 64 + cofs];
        av[mm] = *(const short8*)&vb[(mm * 16 + l16) * 64 + cofs];
      }
#pragma unroll
      for (int mm = 0; mm < 2; mm++) {
#pragma unroll
        for (int nn = 0; nn < 2; nn++)
          accS[mm][nn] = __builtin_amdgcn_mfma_f32_16x16x32_bf16(ak[mm], av[nn], accS[mm][nn], 0, 0, 0);
        accZ[mm] = __builtin_amdgcn_mfma_f32_16x16x32_bf16(ak[mm], ones, accZ[mm], 0, 0, 0);
      }
    }
  }

  // write bf16 partials frag-major (coalesced 8B stores, no atomics)
  unsigned short* Spb = Sp + (size_t)(b * 16 + grp) * 4096 + chunk * 1024;
#pragma unroll
  for (int mm = 0; mm < 2; mm++)
#pragma unroll
    for (int nn = 0; nn < 2; nn++) {
      bf16x4 sv;
#pragma unroll
      for (int r = 0; r < 4; r++) sv[r] = (short)f2bf(accS[mm][nn][r]);
      *(bf16x4*)&Spb[(mm * 2 + nn) * 256 + l * 4] = sv;
    }
  if (l16 == 0) {
#pragma unroll
    for (int mm = 0; mm < 2; mm++) {
      bf16x4 zv;
#pragma unroll
      for (int r = 0; r < 4; r++) zv[r] = (short)f2bf(accZ[mm][r]);
      *(bf16x4*)&Zp[(b * 16 + grp) * 128 + chunk * 32 + mm * 16 + quad * 4] = zv;
    }
  }
}

// ---------------- K2: reduce partials + context + fold w_out -> Mtf ----------------
// grid 512 = 32 b * 16 slices; each slice owns 8 context rows (one head).
__global__ __launch_bounds__(256) void k2_ctx(
    const unsigned short* __restrict__ Sp, const unsigned short* __restrict__ Zp,
    const float* __restrict__ memkv, const float* __restrict__ wout,
    unsigned short* __restrict__ Mtf) {
  __shared__ float wl[128 * 33];   // wout[:, h*32 .. +32] staged, padded
  __shared__ float Cs[8 * 32];     // context rows [hdi][e]
  __shared__ float zsh[8];
  __shared__ float zinv_s[8];
  const int b = blockIdx.x >> 4, sl = blockIdx.x & 15, tid = threadIdx.x;
  const int hd0 = sl * 8, h = hd0 >> 5;
  // stage wout column block (coalesced 128B runs)
  for (int i = tid; i < 4096; i += 256) {
    int o = i >> 5, e = i & 31;
    wl[o * 33 + e] = wout[o * 128 + h * 32 + e];
  }
  // Z reduce: tid = hdi*32 + g (g<16 used), shuffle within 32-lane segments
  {
    int hdi = tid >> 5, g = tid & 31;
    float zp = (g < 16) ? bf2f(Zp[(b * 16 + g) * 128 + hd0 + hdi]) : 0.f;
#pragma unroll
    for (int s2 = 1; s2 < 32; s2 <<= 1) zp += __shfl_xor(zp, s2, 32);
    if (g == 0) zsh[hdi] = zp;
  }
  __syncthreads();
  if (tid < 8) {
    int hd = hd0 + tid;
    float zm = 0.f;
#pragma unroll
    for (int j = 0; j < 4; j++) zm += __expf(memkv[hd * 4 + j]);
    zinv_s[tid] = 1.0f / (zsh[tid] + zm);
  }
  __syncthreads();
  // S reduce: one (hdi, e) cell per thread
  {
    int hdi = tid >> 5, e = tid & 31;
    int hd = hd0 + hdi, d = hd & 31;
    int fofs = h * 1024 + ((d >> 4) * 2 + (e >> 4)) * 256 + ((e & 15) + ((d >> 2) & 3) * 16) * 4 + (d & 3);
    const unsigned short* Spb = Sp + (size_t)b * 65536 + fofs;
    float s = 0.f;
#pragma unroll
    for (int g = 0; g < 16; g++) s += bf2f(Spb[g * 4096]);
    float sm = 0.f;
#pragma unroll
    for (int j = 0; j < 4; j++)
      sm += __expf(memkv[hd * 4 + j]) * memkv[512 + (h * 32 + e) * 4 + j];
    Cs[hdi * 32 + e] = (s + sm) * zinv_s[hdi];
  }
  __syncthreads();
  // fold wout: 4 outputs per thread
  for (int i = tid; i < 1024; i += 256) {
    int o = i & 127, hdi = i >> 7;
    float a = 0.f;
#pragma unroll
    for (int e = 0; e < 32; e++) a += wl[o * 33 + e] * Cs[hdi * 32 + e];
    int hd = hd0 + hdi;
    int f = (o >> 4) * 4 + h;
    int lane = (o & 15) + (((hd >> 3) & 3) << 4);
    Mtf[(size_t)b * 16384 + f * 512 + lane * 8 + (hd & 7)] = f2bf(a);
  }
}

// ---------------- K3: out = Mtf x q + b_out (MFMA, NO LDS, NO barrier) ----------------
// grid 2048 = 32 b * 64 tiles. Each wave loads its 16 B-frags directly from
// frag-major qbf (other waves' duplicate reads hit L1/L2); fire-and-forget.
__global__ __launch_bounds__(256) void k3_out(
    const unsigned short* __restrict__ qbf, const unsigned short* __restrict__ Mtf,
    const float* __restrict__ bout, float* __restrict__ out) {
  const int b = blockIdx.x >> 6, tile = blockIdx.x & 63;
  const int tid = threadIdx.x;
  const int l = tid & 63, quad = l >> 4, l16 = l & 15;
  const int chunk = __builtin_amdgcn_readfirstlane(tid >> 6);
  const short8* Mv = (const short8*)Mtf;
  const short8* qv = (const short8*)qbf + (size_t)(b * 64 + tile) * 1024;
  short8 afr[2][4];
#pragma unroll
  for (int mm = 0; mm < 2; mm++)
#pragma unroll
    for (int k0 = 0; k0 < 4; k0++)
      afr[mm][k0] = Mv[((size_t)b * 32 + (chunk * 2 + mm) * 4 + k0) * 64 + l];
  f32x4 acc[2][4] = {};
#pragma unroll
  for (int hh = 0; hh < 2; hh++) {   // frag halves: k0 = 2hh, 2hh+1
    short8 bfr[8];
#pragma unroll
    for (int j = 0; j < 8; j++) bfr[j] = qv[(hh * 8 + j) * 64 + l];
#pragma unroll
    for (int kk = 0; kk < 2; kk++) {
      int k0 = hh * 2 + kk;
#pragma unroll
      for (int mm = 0; mm < 2; mm++)
#pragma unroll
        for (int n0 = 0; n0 < 4; n0++)
          acc[mm][n0] = __builtin_amdgcn_mfma_f32_16x16x32_bf16(afr[mm][k0], bfr[kk * 4 + n0], acc[mm][n0], 0, 0, 0);
    }
  }
  // direct stores: col = px on lane (16x4B = 64B contiguous per 16-lane group)
  float* ob = out + (size_t)b * 524288 + tile * 64;
#pragma unroll
  for (int mm = 0; mm < 2; mm++)
#pragma unroll
    for (int r = 0; r < 4; r++) {
      int o = chunk * 32 + mm * 16 + quad * 4 + r;
      float bv = bout[o];
#pragma unroll
      for (int n0 = 0; n0 < 4; n0++)
        ob[(size_t)o * 4096 + n0 * 16 + l16] = acc[mm][n0][r] + bv;
    }
}

extern "C" void kernel_launch(void* const* d_in, const int* in_sizes, int n_in,
                              void* d_out, int out_size, void* d_ws, size_t ws_size,
                              hipStream_t stream) {
  const float* x     = (const float*)d_in[0];
  const float* g     = (const float*)d_in[1];
  const float* wqkv  = (const float*)d_in[2];
  const float* memkv = (const float*)d_in[3];
  const float* wout  = (const float*)d_in[4];
  const float* bout  = (const float*)d_in[5];
  float* out = (float*)d_out;
  float* ws = (float*)d_ws;
  unsigned short* Sp  = (unsigned short*)ws;
  unsigned short* Zp  = (unsigned short*)(ws + 2097152);
  unsigned short* Mtf = (unsigned short*)(ws + 2162688);
  unsigned short* Wf  = (unsigned short*)(ws + 2424832);
  float* gs  = ws + 2449408;
  unsigned short* qbf = (unsigned short*)(ws + 2449536);

  k0_init<<<128, 256, 0, stream>>>(wqkv, g, ws);
  k1_qkv<<<512, 256, 0, stream>>>(x, Wf, gs, Sp, Zp, qbf);
  k2_ctx<<<512, 256, 0, stream>>>(Sp, Zp, memkv, wout, Mtf);
  k3_out<<<2048, 256, 0, stream>>>(qbf, Mtf, bout, out);
}